// Round 11
// baseline (297.681 us; speedup 1.0000x reference)
//
#include <hip/hip_runtime.h>
#include <hip/hip_bf16.h>

#define NN 50000
#define NE 1600000
#define F 128
#define CAP 96
#define NBUCK 391   // ceil(NN/128)

typedef short short8 __attribute__((ext_vector_type(8)));
typedef float f32x4 __attribute__((ext_vector_type(4)));
typedef unsigned short u16x4 __attribute__((ext_vector_type(4)));
typedef unsigned short u16x8 __attribute__((ext_vector_type(8)));

__device__ inline unsigned short bf16rne(float f) {
  unsigned u = __builtin_bit_cast(unsigned, f);
  u += 0x7FFFu + ((u >> 16) & 1u);
  return (unsigned short)(u >> 16);
}
__device__ inline float bf16f(unsigned short s) {
  unsigned u = ((unsigned)s) << 16;
  return __builtin_bit_cast(float, u);
}
__device__ inline float bflo(unsigned v) { return __builtin_bit_cast(float, v << 16); }
__device__ inline float bfhi(unsigned v) { return __builtin_bit_cast(float, v & 0xFFFF0000u); }

__global__ void zero_i32(int* __restrict__ p, int n) {
  int i = blockIdx.x * blockDim.x + threadIdx.x;
  if (i < n) p[i] = 0;
}

// O = A @ Wfc  (all 128x128 row-major f32)
__global__ void mat_compose(const float* __restrict__ A, const float* __restrict__ Wfc,
                            float* __restrict__ O) {
  int idx = blockIdx.x * 256 + threadIdx.x;  // < 16384
  int k = idx >> 7, n = idx & 127;
  float s = 0.f;
  for (int j = 0; j < 128; ++j) s += A[k * 128 + j] * Wfc[j * 128 + n];
  O[idx] = s;
}

// bout[n] = sum_k b2[k]*Wfc[k][n] + bfc[n]
__global__ void bias_compose(const float* __restrict__ b2, const float* __restrict__ Wfc,
                             const float* __restrict__ bfc, float* __restrict__ bout) {
  int n = threadIdx.x;  // 128 threads
  float s = bfc[n];
  for (int k = 0; k < 128; ++k) s += b2[k] * Wfc[k * 128 + n];
  bout[n] = s;
}

// ---- 4-phase binned CSR build (bucket = dst>>7, 391 buckets x 128 nodes) ----

__global__ __launch_bounds__(256) void ebin_hist(const int* __restrict__ dst,
                                                 int* __restrict__ ghist) {
  __shared__ int lh[512];
  int t = threadIdx.x;
  lh[t] = 0;
  lh[t + 256] = 0;
  __syncthreads();
  int base = blockIdx.x * 3125;
  for (int k = t; k < 3125; k += 256) atomicAdd(&lh[dst[base + k] >> 7], 1);
  __syncthreads();
  if (t < NBUCK && lh[t]) atomicAdd(&ghist[t], lh[t]);
  int t2 = t + 256;
  if (t2 < NBUCK && lh[t2]) atomicAdd(&ghist[t2], lh[t2]);
}

__global__ void ebin_scan(const int* __restrict__ ghist, int* __restrict__ gbase,
                          int* __restrict__ gcur) {
  __shared__ int s[512];
  int t = threadIdx.x;
  s[t] = (t < NBUCK) ? ghist[t] : 0;
  __syncthreads();
  for (int d = 1; d < 512; d <<= 1) {
    int x = (t >= d) ? s[t - d] : 0;
    __syncthreads();
    s[t] += x;
    __syncthreads();
  }
  int ex = (t == 0) ? 0 : s[t - 1];
  if (t < NBUCK) {
    gbase[t] = ex;
    gcur[t] = ex;
  }
  if (t == NBUCK) gbase[NBUCK] = s[NBUCK - 1];
}

__global__ __launch_bounds__(256) void ebin_scatter(const int* __restrict__ src,
                                                    const int* __restrict__ dst,
                                                    int* __restrict__ gcur,
                                                    unsigned* __restrict__ ebin) {
  __shared__ int lh[512], lbase[512], lcur[512];
  int t = threadIdx.x;
  lh[t] = 0; lh[t + 256] = 0;
  lcur[t] = 0; lcur[t + 256] = 0;
  __syncthreads();
  int base = blockIdx.x * 3125;
  for (int k = t; k < 3125; k += 256) atomicAdd(&lh[dst[base + k] >> 7], 1);
  __syncthreads();
  if (t < NBUCK && lh[t]) lbase[t] = atomicAdd(&gcur[t], lh[t]);
  int t2 = t + 256;
  if (t2 < NBUCK && lh[t2]) lbase[t2] = atomicAdd(&gcur[t2], lh[t2]);
  __syncthreads();
  for (int k = t; k < 3125; k += 256) {
    int d = dst[base + k];
    int b = d >> 7;
    int off = atomicAdd(&lcur[b], 1);
    ebin[lbase[b] + off] = ((unsigned)(d & 127) << 16) | (unsigned)src[base + k];
  }
}

// Phase D: one block per 128-node bucket; rows zero-filled (padding = node 0,
// always valid) so agg gathers full batches unconditionally.
__global__ __launch_bounds__(256) void bucket_csr(const unsigned* __restrict__ ebin,
                                                  const int* __restrict__ gbase,
                                                  int* __restrict__ cnt,
                                                  unsigned short* __restrict__ esrcPad) {
  __shared__ int lcnt[128];
  __shared__ unsigned short rows[128 * CAP];  // 24576 B
  int t = threadIdx.x;
  int b = blockIdx.x;
  if (t < 128) lcnt[t] = 0;
  unsigned* rz = (unsigned*)rows;
  for (int i = t; i < (128 * CAP) / 2; i += 256) rz[i] = 0;
  __syncthreads();
  int s0 = gbase[b], s1 = gbase[b + 1];
  for (int i = s0 + t; i < s1; i += 256) {
    unsigned v = ebin[i];
    int dl = v >> 16;
    int p = atomicAdd(&lcnt[dl], 1);
    if (p < CAP) rows[dl * CAP + p] = (unsigned short)(v & 0xFFFFu);
  }
  __syncthreads();
  int node = b * 128 + t;
  if (t < 128 && node < NN) cnt[node] = lcnt[t];
  int nvalid = min(128, NN - b * 128);
  int limit = (nvalid * CAP) >> 1;  // u32 count
  const unsigned* lsrc = (const unsigned*)rows;
  unsigned* gdst = (unsigned*)(esrcPad + (size_t)b * 128 * CAP);
  for (int i = t; i < limit; i += 256) gdst[i] = lsrc[i];
}

// f32 [node][128] -> bf16 chunked [f/32][node][32] (gather table) AND
// row-major bf16 X[node][256] cols 0..127 (combine A operand)
__global__ void tobf16_chunk(const float* __restrict__ in,
                             unsigned short* __restrict__ chk,
                             unsigned short* __restrict__ X) {
  int i = blockIdx.x * 256 + threadIdx.x;  // i < NN*32
  if (i >= NN * 32) return;
  int node = i >> 5;
  int q = i & 31;            // float4 index within row; f0 = q*4
  int p = q >> 3;            // chunk
  float4 v = ((const float4*)in)[i];
  u16x4 o;
  o[0] = bf16rne(v.x);
  o[1] = bf16rne(v.y);
  o[2] = bf16rne(v.z);
  o[3] = bf16rne(v.w);
  ((u16x4*)chk)[((size_t)p * NN + node) * 8 + (q & 7)] = o;
  *(u16x4*)(X + (size_t)node * 256 + q * 4) = o;
}

// quarter-wave (16 lanes) per node; gathers 64B rows from a 3.2MB L2-resident
// pass window; full 16-wide zero-padded batches, masked accumulate.
// nt hints on the index stream so it doesn't evict the feature window.
__global__ __launch_bounds__(256) void agg_pass(const unsigned* __restrict__ tbl,
                                                const int* __restrict__ cnt,
                                                const unsigned short* __restrict__ esrcPad,
                                                unsigned short* __restrict__ X, int pass) {
  int t = threadIdx.x;
  int node = blockIdx.x * 16 + (t >> 4);
  if (node >= NN) return;
  int l = t & 15;
  int e = __builtin_nontemporal_load(&cnt[node]);
  if (e > CAP) e = CAP;
  const unsigned short* ep = esrcPad + (size_t)node * CAP;
  float ax0 = 0.f, ay0 = 0.f, ax1 = 0.f, ay1 = 0.f;
  int nb = (e + 15) >> 4;  // full 16-edge batches, zero-padded
  for (int b = 0; b < nb; ++b) {
    int i = b * 16;
    u16x8 ua = __builtin_nontemporal_load((const u16x8*)(ep + i));
    u16x8 ub = __builtin_nontemporal_load((const u16x8*)(ep + i + 8));
    unsigned v[16];
#pragma unroll
    for (int j = 0; j < 8; ++j) v[j] = tbl[(size_t)ua[j] * 16 + l];
#pragma unroll
    for (int j = 0; j < 8; ++j) v[8 + j] = tbl[(size_t)ub[j] * 16 + l];
    int rem = e - i;  // >= 1
#pragma unroll
    for (int j = 0; j < 16; ++j) {
      unsigned x = (j < rem) ? v[j] : 0u;
      if (j & 1) { ax1 += bflo(x); ay1 += bfhi(x); }
      else       { ax0 += bflo(x); ay0 += bfhi(x); }
    }
  }
  float inv = 1.0f / (float)max(e, 1);
  unsigned w = (unsigned)bf16rne((ax0 + ax1) * inv) |
               ((unsigned)bf16rne((ay0 + ay1) * inv) << 16);
  *(unsigned*)(X + (size_t)node * 256 + 128 + pass * 32 + l * 2) = w;
}

// Build transposed bf16 hi/lo weight arrays: WT[n][k], k in [0,256).
__global__ void wprep(const float* __restrict__ Ws, const float* __restrict__ Wn,
                      unsigned short* __restrict__ hi, unsigned short* __restrict__ lo) {
  int i = blockIdx.x * 256 + threadIdx.x;  // < 128*256
  int k = i & 255;
  int n = i >> 8;
  float w = (k < 128) ? Ws[(size_t)k * F + n] : Wn[(size_t)(k - 128) * F + n];
  unsigned short h = bf16rne(w);
  hi[i] = h;
  lo[i] = bf16rne(w - bf16f(h));
}

// C = act(X @ W + bias), X bf16 [NN][256], W hi/lo bf16 [128][256].
// W-STATIONARY: wave owns 32 output cols; its 32 W frags (hi+lo, full K)
// are loaded ONCE into registers (statically indexed -> guaranteed regs,
// ~128 VGPR), then 4 row-tiles stream through with 8 A-loads + 32 MFMAs
// each. Inner loop has zero W traffic and no per-ks dependent load chain.
template <bool RELU, bool L1>
__global__ __launch_bounds__(256) void combine_mfma(
    const unsigned short* __restrict__ X,
    const unsigned short* __restrict__ WThi, const unsigned short* __restrict__ WTlo,
    const float* __restrict__ bias, float* __restrict__ Cf,
    unsigned short* __restrict__ Xout, unsigned short* __restrict__ Cb) {
  const int K = 256;
  int wave = threadIdx.x >> 6;   // col group: cols [wave*32, wave*32+32)
  int lane = threadIdx.x & 63;
  int lm = lane & 15;  // A row-in-tile / W col-in-tile / C col-in-tile
  int lk = lane >> 4;  // k-chunk select / C row-group
  int R0 = blockIdx.x * 64;

  // --- W prologue: 32 frags, resident for the whole kernel ---
  short8 wh[2][8], wl[2][8];
  float bs[2];
#pragma unroll
  for (int t2 = 0; t2 < 2; ++t2) {
    int col = (wave * 2 + t2) * 16 + lm;
    bs[t2] = bias[col];
#pragma unroll
    for (int ks = 0; ks < 8; ++ks) {
      size_t widx = (size_t)col * K + ks * 32 + lk * 8;
      wh[t2][ks] = *(const short8*)(WThi + widx);
      wl[t2][ks] = *(const short8*)(WTlo + widx);
    }
  }

  // --- stream 4 row-tiles ---
#pragma unroll
  for (int rt = 0; rt < 4; ++rt) {
    int Rt = R0 + rt * 16;
    if (Rt >= NN) break;
    int rA = Rt + lm;
    if (rA >= NN) rA = NN - 1;  // clamped rows compute garbage, never stored
    short8 a[8];
    const unsigned short* xp = X + (size_t)rA * K + lk * 8;
#pragma unroll
    for (int ks = 0; ks < 8; ++ks) a[ks] = *(const short8*)(xp + ks * 32);

    f32x4 acc[2];
#pragma unroll
    for (int t2 = 0; t2 < 2; ++t2) acc[t2] = (f32x4){bs[t2], bs[t2], bs[t2], bs[t2]};

#pragma unroll
    for (int ks = 0; ks < 8; ++ks) {
#pragma unroll
      for (int t2 = 0; t2 < 2; ++t2) {
        acc[t2] = __builtin_amdgcn_mfma_f32_16x16x32_bf16(a[ks], wh[t2][ks], acc[t2], 0, 0, 0);
        acc[t2] = __builtin_amdgcn_mfma_f32_16x16x32_bf16(a[ks], wl[t2][ks], acc[t2], 0, 0, 0);
      }
    }

#pragma unroll
    for (int t2 = 0; t2 < 2; ++t2) {
#pragma unroll
      for (int r = 0; r < 4; ++r) {
        int row = Rt + lk * 4 + r;
        if (row < NN) {
          float v = acc[t2][r];
          if (RELU) v = fmaxf(v, 0.f);
          int f = (wave * 2 + t2) * 16 + lm;
          if (L1) {
            unsigned short b = bf16rne(v);
            Xout[(size_t)row * 256 + f] = b;                        // next-layer A
            Cb[((size_t)wave * NN + row) * 32 + t2 * 16 + lm] = b;  // gather table
          } else {
            Cf[(size_t)row * F + f] = v;
          }
        }
      }
    }
  }
}

extern "C" void kernel_launch(void* const* d_in, const int* in_sizes, int n_in,
                              void* d_out, int out_size, void* d_ws, size_t ws_size,
                              hipStream_t stream) {
  const float* feat = (const float*)d_in[0];
  const int* src = (const int*)d_in[1];
  const int* dst = (const int*)d_in[2];
  const float* Ws1 = (const float*)d_in[3];
  const float* Wn1 = (const float*)d_in[4];
  const float* b1 = (const float*)d_in[5];
  const float* Ws2 = (const float*)d_in[6];
  const float* Wn2 = (const float*)d_in[7];
  const float* b2 = (const float*)d_in[8];
  const float* Wfc = (const float*)d_in[9];
  const float* bfc = (const float*)d_in[10];
  float* out = (float*)d_out;

  // workspace layout; every region 16B-aligned
  unsigned short* esrcPad = (unsigned short*)d_ws;        // NN*CAP u16 (9.6MB)
  int* cnt = (int*)(esrcPad + (size_t)NN * CAP);          // 50048 ints
  int* ghist = cnt + 50048;                               // 512
  int* gbase = ghist + 512;                               // 512
  int* gcur = gbase + 512;                                // 512
  unsigned* ebin = (unsigned*)(gcur + 512);               // NE u32 (6.4MB)
  unsigned short* X1 = (unsigned short*)(ebin + NE);      // NN*256 bf16 (25.6MB)
  unsigned short* X2 = X1 + (size_t)NN * 256;             // NN*256 bf16 (25.6MB)
  unsigned short* w1hi = X2 + (size_t)NN * 256;           // 128*256
  unsigned short* w1lo = w1hi + 128 * 256;
  unsigned short* w2hi = w1lo + 128 * 256;
  unsigned short* w2lo = w2hi + 128 * 256;
  float* wsf = (float*)(w2lo + 128 * 256);                // 128*128 f32 (Ws2@Wfc)
  float* wnf = wsf + 128 * 128;                           // 128*128 f32 (Wn2@Wfc)
  float* bfF = wnf + 128 * 128;                           // 128 f32
  unsigned short* hbf = (unsigned short*)(bfF + 128);     // NN*128 bf16 chunked [4][NN][32]

  // fold layer-2 weights through the FC (no nonlinearity between them)
  mat_compose<<<64, 256, 0, stream>>>(Ws2, Wfc, wsf);
  mat_compose<<<64, 256, 0, stream>>>(Wn2, Wfc, wnf);
  bias_compose<<<1, 128, 0, stream>>>(b2, Wfc, bfc, bfF);

  // weight + feature prep (independent of CSR build)
  wprep<<<128, 256, 0, stream>>>(Ws1, Wn1, w1hi, w1lo);
  wprep<<<128, 256, 0, stream>>>(wsf, wnf, w2hi, w2lo);
  tobf16_chunk<<<(NN * 32 + 255) / 256, 256, 0, stream>>>(feat, hbf, X1);

  // binned CSR build (512-block phases, 391 buckets x 128 nodes)
  zero_i32<<<2, 256, 0, stream>>>(ghist, 512);
  ebin_hist<<<512, 256, 0, stream>>>(dst, ghist);
  ebin_scan<<<1, 512, 0, stream>>>(ghist, gbase, gcur);
  ebin_scatter<<<512, 256, 0, stream>>>(src, dst, gcur, ebin);
  bucket_csr<<<NBUCK, 256, 0, stream>>>(ebin, gbase, cnt, esrcPad);

  const int aggBlocks = (NN + 15) / 16;  // 16 nodes (quarter-waves) per block
  const int gemBlocks = (NN + 63) / 64;  // 64 rows per block; wave = 32 cols

  // layer 1: 4 feature-chunk passes into X1 cols 128..255
  for (int p = 0; p < 4; ++p)
    agg_pass<<<aggBlocks, 256, 0, stream>>>((const unsigned*)hbf + (size_t)p * NN * 16,
                                            cnt, esrcPad, X1, p);
  combine_mfma<true, true><<<gemBlocks, 256, 0, stream>>>(X1, w1hi, w1lo, b1,
                                                          nullptr, X2, hbf);

  // layer 2 + FC folded (hbf now holds bf16 relu(h1)); agg into X2 cols 128..255
  for (int p = 0; p < 4; ++p)
    agg_pass<<<aggBlocks, 256, 0, stream>>>((const unsigned*)hbf + (size_t)p * NN * 16,
                                            cnt, esrcPad, X2, p);
  combine_mfma<false, false><<<gemBlocks, 256, 0, stream>>>(X2, w2hi, w2lo, bfF,
                                                            out, nullptr, nullptr);
}

// Round 12
// 262.292 us; speedup vs baseline: 1.1349x; 1.1349x over previous
//
#include <hip/hip_runtime.h>
#include <hip/hip_bf16.h>

#define NN 50000
#define NE 1600000
#define F 128
#define CAP 96
#define NBUCK 391   // ceil(NN/128)

typedef short short8 __attribute__((ext_vector_type(8)));
typedef float f32x4 __attribute__((ext_vector_type(4)));
typedef unsigned short u16x4 __attribute__((ext_vector_type(4)));
typedef unsigned short u16x8 __attribute__((ext_vector_type(8)));

__device__ inline unsigned short bf16rne(float f) {
  unsigned u = __builtin_bit_cast(unsigned, f);
  u += 0x7FFFu + ((u >> 16) & 1u);
  return (unsigned short)(u >> 16);
}
__device__ inline float bf16f(unsigned short s) {
  unsigned u = ((unsigned)s) << 16;
  return __builtin_bit_cast(float, u);
}
__device__ inline float bflo(unsigned v) { return __builtin_bit_cast(float, v << 16); }
__device__ inline float bfhi(unsigned v) { return __builtin_bit_cast(float, v & 0xFFFF0000u); }

__global__ void zero_i32(int* __restrict__ p, int n) {
  int i = blockIdx.x * blockDim.x + threadIdx.x;
  if (i < n) p[i] = 0;
}

// O = A @ Wfc  (all 128x128 row-major f32)
__global__ void mat_compose(const float* __restrict__ A, const float* __restrict__ Wfc,
                            float* __restrict__ O) {
  int idx = blockIdx.x * 256 + threadIdx.x;  // < 16384
  int k = idx >> 7, n = idx & 127;
  float s = 0.f;
  for (int j = 0; j < 128; ++j) s += A[k * 128 + j] * Wfc[j * 128 + n];
  O[idx] = s;
}

// bout[n] = sum_k b2[k]*Wfc[k][n] + bfc[n]
__global__ void bias_compose(const float* __restrict__ b2, const float* __restrict__ Wfc,
                             const float* __restrict__ bfc, float* __restrict__ bout) {
  int n = threadIdx.x;  // 128 threads
  float s = bfc[n];
  for (int k = 0; k < 128; ++k) s += b2[k] * Wfc[k * 128 + n];
  bout[n] = s;
}

// ---- 4-phase binned CSR build (bucket = dst>>7, 391 buckets x 128 nodes) ----

__global__ __launch_bounds__(256) void ebin_hist(const int* __restrict__ dst,
                                                 int* __restrict__ ghist) {
  __shared__ int lh[512];
  int t = threadIdx.x;
  lh[t] = 0;
  lh[t + 256] = 0;
  __syncthreads();
  int base = blockIdx.x * 3125;
  for (int k = t; k < 3125; k += 256) atomicAdd(&lh[dst[base + k] >> 7], 1);
  __syncthreads();
  if (t < NBUCK && lh[t]) atomicAdd(&ghist[t], lh[t]);
  int t2 = t + 256;
  if (t2 < NBUCK && lh[t2]) atomicAdd(&ghist[t2], lh[t2]);
}

__global__ void ebin_scan(const int* __restrict__ ghist, int* __restrict__ gbase,
                          int* __restrict__ gcur) {
  __shared__ int s[512];
  int t = threadIdx.x;
  s[t] = (t < NBUCK) ? ghist[t] : 0;
  __syncthreads();
  for (int d = 1; d < 512; d <<= 1) {
    int x = (t >= d) ? s[t - d] : 0;
    __syncthreads();
    s[t] += x;
    __syncthreads();
  }
  int ex = (t == 0) ? 0 : s[t - 1];
  if (t < NBUCK) {
    gbase[t] = ex;
    gcur[t] = ex;
  }
  if (t == NBUCK) gbase[NBUCK] = s[NBUCK - 1];
}

__global__ __launch_bounds__(256) void ebin_scatter(const int* __restrict__ src,
                                                    const int* __restrict__ dst,
                                                    int* __restrict__ gcur,
                                                    unsigned* __restrict__ ebin) {
  __shared__ int lh[512], lbase[512], lcur[512];
  int t = threadIdx.x;
  lh[t] = 0; lh[t + 256] = 0;
  lcur[t] = 0; lcur[t + 256] = 0;
  __syncthreads();
  int base = blockIdx.x * 3125;
  for (int k = t; k < 3125; k += 256) atomicAdd(&lh[dst[base + k] >> 7], 1);
  __syncthreads();
  if (t < NBUCK && lh[t]) lbase[t] = atomicAdd(&gcur[t], lh[t]);
  int t2 = t + 256;
  if (t2 < NBUCK && lh[t2]) lbase[t2] = atomicAdd(&gcur[t2], lh[t2]);
  __syncthreads();
  for (int k = t; k < 3125; k += 256) {
    int d = dst[base + k];
    int b = d >> 7;
    int off = atomicAdd(&lcur[b], 1);
    ebin[lbase[b] + off] = ((unsigned)(d & 127) << 16) | (unsigned)src[base + k];
  }
}

// Phase D: one block per 128-node bucket; rows zero-filled (padding = node 0,
// always valid) so agg gathers full batches unconditionally.
__global__ __launch_bounds__(256) void bucket_csr(const unsigned* __restrict__ ebin,
                                                  const int* __restrict__ gbase,
                                                  int* __restrict__ cnt,
                                                  unsigned short* __restrict__ esrcPad) {
  __shared__ int lcnt[128];
  __shared__ unsigned short rows[128 * CAP];  // 24576 B
  int t = threadIdx.x;
  int b = blockIdx.x;
  if (t < 128) lcnt[t] = 0;
  unsigned* rz = (unsigned*)rows;
  for (int i = t; i < (128 * CAP) / 2; i += 256) rz[i] = 0;
  __syncthreads();
  int s0 = gbase[b], s1 = gbase[b + 1];
  for (int i = s0 + t; i < s1; i += 256) {
    unsigned v = ebin[i];
    int dl = v >> 16;
    int p = atomicAdd(&lcnt[dl], 1);
    if (p < CAP) rows[dl * CAP + p] = (unsigned short)(v & 0xFFFFu);
  }
  __syncthreads();
  int node = b * 128 + t;
  if (t < 128 && node < NN) cnt[node] = lcnt[t];
  int nvalid = min(128, NN - b * 128);
  int limit = (nvalid * CAP) >> 1;  // u32 count
  const unsigned* lsrc = (const unsigned*)rows;
  unsigned* gdst = (unsigned*)(esrcPad + (size_t)b * 128 * CAP);
  for (int i = t; i < limit; i += 256) gdst[i] = lsrc[i];
}

// f32 [node][128] -> bf16 chunked [f/32][node][32] (gather table) AND
// row-major bf16 X[node][256] cols 0..127 (combine A operand)
__global__ void tobf16_chunk(const float* __restrict__ in,
                             unsigned short* __restrict__ chk,
                             unsigned short* __restrict__ X) {
  int i = blockIdx.x * 256 + threadIdx.x;  // i < NN*32
  if (i >= NN * 32) return;
  int node = i >> 5;
  int q = i & 31;            // float4 index within row; f0 = q*4
  int p = q >> 3;            // chunk
  float4 v = ((const float4*)in)[i];
  u16x4 o;
  o[0] = bf16rne(v.x);
  o[1] = bf16rne(v.y);
  o[2] = bf16rne(v.z);
  o[3] = bf16rne(v.w);
  ((u16x4*)chk)[((size_t)p * NN + node) * 8 + (q & 7)] = o;
  *(u16x4*)(X + (size_t)node * 256 + q * 4) = o;
}

// ALL 4 feature-chunk passes in one launch. pass = (blockIdx&7)&3: with
// round-robin block->XCD dispatch, each XCD gathers from exactly ONE 3.2MB
// window (fits its 4MB L2) while all 4 passes run concurrently (4x the
// resident waves of the serial-pass scheme, 6 fewer launches).
// Quarter-wave (16 lanes) per node; full 16-wide zero-padded batches.
__global__ __launch_bounds__(256) void agg_all(const unsigned* __restrict__ tbl,
                                               const int* __restrict__ cnt,
                                               const unsigned short* __restrict__ esrcPad,
                                               unsigned short* __restrict__ X) {
  int bid = blockIdx.x;
  int xcd = bid & 7;
  int pass = xcd & 3;
  int nodeBase = (bid >> 3) * 32 + ((xcd >> 2) & 1) * 16;
  int t = threadIdx.x;
  int node = nodeBase + (t >> 4);
  if (node >= NN) return;
  const unsigned* tblp = tbl + (size_t)pass * NN * 16;
  int l = t & 15;
  int e = cnt[node];
  if (e > CAP) e = CAP;
  const unsigned short* ep = esrcPad + (size_t)node * CAP;
  float ax0 = 0.f, ay0 = 0.f, ax1 = 0.f, ay1 = 0.f;
  int nb = (e + 15) >> 4;  // full 16-edge batches, zero-padded
  for (int b = 0; b < nb; ++b) {
    int i = b * 16;
    u16x8 ua = *(const u16x8*)(ep + i);
    u16x8 ub = *(const u16x8*)(ep + i + 8);
    unsigned v[16];
#pragma unroll
    for (int j = 0; j < 8; ++j) v[j] = tblp[(size_t)ua[j] * 16 + l];
#pragma unroll
    for (int j = 0; j < 8; ++j) v[8 + j] = tblp[(size_t)ub[j] * 16 + l];
    int rem = e - i;  // >= 1
#pragma unroll
    for (int j = 0; j < 16; ++j) {
      unsigned x = (j < rem) ? v[j] : 0u;
      if (j & 1) { ax1 += bflo(x); ay1 += bfhi(x); }
      else       { ax0 += bflo(x); ay0 += bfhi(x); }
    }
  }
  float inv = 1.0f / (float)max(e, 1);
  unsigned w = (unsigned)bf16rne((ax0 + ax1) * inv) |
               ((unsigned)bf16rne((ay0 + ay1) * inv) << 16);
  *(unsigned*)(X + (size_t)node * 256 + 128 + pass * 32 + l * 2) = w;
}

// Build transposed bf16 hi/lo weight arrays: WT[n][k], k in [0,256).
__global__ void wprep(const float* __restrict__ Ws, const float* __restrict__ Wn,
                      unsigned short* __restrict__ hi, unsigned short* __restrict__ lo) {
  int i = blockIdx.x * 256 + threadIdx.x;  // < 128*256
  int k = i & 255;
  int n = i >> 8;
  float w = (k < 128) ? Ws[(size_t)k * F + n] : Wn[(size_t)(k - 128) * F + n];
  unsigned short h = bf16rne(w);
  hi[i] = h;
  lo[i] = bf16rne(w - bf16f(h));
}

// C = act(X @ W + bias), X bf16 [NN][256], W hi/lo bf16 [128][256].
// Wave owns 16 cols: W = 16 frags = 64 VGPR (statically indexed -> resident)
// x 2 row-tiles (a0/a1: two interleaved MFMA chains). Block = 4 waves =
// 64 cols x 32 rows; grid 3126 = 12504 waves.
template <bool RELU, bool L1>
__global__ __launch_bounds__(256) void combine_mfma(
    const unsigned short* __restrict__ X,
    const unsigned short* __restrict__ WThi, const unsigned short* __restrict__ WTlo,
    const float* __restrict__ bias, float* __restrict__ Cf,
    unsigned short* __restrict__ Xout, unsigned short* __restrict__ Cb) {
  const int K = 256;
  int wave = threadIdx.x >> 6;
  int lane = threadIdx.x & 63;
  int lm = lane & 15;  // A row-in-tile / W col-in-tile / C col-in-tile
  int lk = lane >> 4;  // k-chunk select / C row-group
  int cg = (blockIdx.x & 1) * 4 + wave;  // col-tile 0..7
  int R0 = (blockIdx.x >> 1) * 32;
  if (R0 >= NN) return;
  int col = cg * 16 + lm;

  // --- W prologue: 16 frags, resident for the whole kernel (64 VGPR) ---
  short8 wh[8], wl[8];
  float bs = bias[col];
#pragma unroll
  for (int ks = 0; ks < 8; ++ks) {
    size_t widx = (size_t)col * K + ks * 32 + lk * 8;
    wh[ks] = *(const short8*)(WThi + widx);
    wl[ks] = *(const short8*)(WTlo + widx);
  }

  int rA0 = R0 + lm;
  int rA1 = R0 + 16 + lm;
  if (rA0 >= NN) rA0 = NN - 1;  // clamped rows compute garbage, never stored
  if (rA1 >= NN) rA1 = NN - 1;

  short8 a0[8], a1[8];
  {
    const unsigned short* x0 = X + (size_t)rA0 * K + lk * 8;
    const unsigned short* x1 = X + (size_t)rA1 * K + lk * 8;
#pragma unroll
    for (int ks = 0; ks < 8; ++ks) a0[ks] = *(const short8*)(x0 + ks * 32);
#pragma unroll
    for (int ks = 0; ks < 8; ++ks) a1[ks] = *(const short8*)(x1 + ks * 32);
  }

  f32x4 acc0 = (f32x4){bs, bs, bs, bs};
  f32x4 acc1 = (f32x4){bs, bs, bs, bs};
#pragma unroll
  for (int ks = 0; ks < 8; ++ks) {
    acc0 = __builtin_amdgcn_mfma_f32_16x16x32_bf16(a0[ks], wh[ks], acc0, 0, 0, 0);
    acc1 = __builtin_amdgcn_mfma_f32_16x16x32_bf16(a1[ks], wh[ks], acc1, 0, 0, 0);
    acc0 = __builtin_amdgcn_mfma_f32_16x16x32_bf16(a0[ks], wl[ks], acc0, 0, 0, 0);
    acc1 = __builtin_amdgcn_mfma_f32_16x16x32_bf16(a1[ks], wl[ks], acc1, 0, 0, 0);
  }

#pragma unroll
  for (int tile = 0; tile < 2; ++tile) {
    f32x4 acc = tile ? acc1 : acc0;
#pragma unroll
    for (int r = 0; r < 4; ++r) {
      int row = R0 + tile * 16 + lk * 4 + r;
      if (row < NN) {
        float v = acc[r];
        if (RELU) v = fmaxf(v, 0.f);
        if (L1) {
          unsigned short b = bf16rne(v);
          Xout[(size_t)row * 256 + col] = b;                          // next-layer A
          Cb[((size_t)(cg >> 1) * NN + row) * 32 + (col & 31)] = b;   // gather table
        } else {
          Cf[(size_t)row * F + col] = v;
        }
      }
    }
  }
}

extern "C" void kernel_launch(void* const* d_in, const int* in_sizes, int n_in,
                              void* d_out, int out_size, void* d_ws, size_t ws_size,
                              hipStream_t stream) {
  const float* feat = (const float*)d_in[0];
  const int* src = (const int*)d_in[1];
  const int* dst = (const int*)d_in[2];
  const float* Ws1 = (const float*)d_in[3];
  const float* Wn1 = (const float*)d_in[4];
  const float* b1 = (const float*)d_in[5];
  const float* Ws2 = (const float*)d_in[6];
  const float* Wn2 = (const float*)d_in[7];
  const float* b2 = (const float*)d_in[8];
  const float* Wfc = (const float*)d_in[9];
  const float* bfc = (const float*)d_in[10];
  float* out = (float*)d_out;

  // workspace layout; every region 16B-aligned
  unsigned short* esrcPad = (unsigned short*)d_ws;        // NN*CAP u16 (9.6MB)
  int* cnt = (int*)(esrcPad + (size_t)NN * CAP);          // 50048 ints
  int* ghist = cnt + 50048;                               // 512
  int* gbase = ghist + 512;                               // 512
  int* gcur = gbase + 512;                                // 512
  unsigned* ebin = (unsigned*)(gcur + 512);               // NE u32 (6.4MB)
  unsigned short* X1 = (unsigned short*)(ebin + NE);      // NN*256 bf16 (25.6MB)
  unsigned short* X2 = X1 + (size_t)NN * 256;             // NN*256 bf16 (25.6MB)
  unsigned short* w1hi = X2 + (size_t)NN * 256;           // 128*256
  unsigned short* w1lo = w1hi + 128 * 256;
  unsigned short* w2hi = w1lo + 128 * 256;
  unsigned short* w2lo = w2hi + 128 * 256;
  float* wsf = (float*)(w2lo + 128 * 256);                // 128*128 f32 (Ws2@Wfc)
  float* wnf = wsf + 128 * 128;                           // 128*128 f32 (Wn2@Wfc)
  float* bfF = wnf + 128 * 128;                           // 128 f32
  unsigned short* hbf = (unsigned short*)(bfF + 128);     // NN*128 bf16 chunked [4][NN][32]

  // fold layer-2 weights through the FC (no nonlinearity between them)
  mat_compose<<<64, 256, 0, stream>>>(Ws2, Wfc, wsf);
  mat_compose<<<64, 256, 0, stream>>>(Wn2, Wfc, wnf);
  bias_compose<<<1, 128, 0, stream>>>(b2, Wfc, bfc, bfF);

  // weight + feature prep (independent of CSR build)
  wprep<<<128, 256, 0, stream>>>(Ws1, Wn1, w1hi, w1lo);
  wprep<<<128, 256, 0, stream>>>(wsf, wnf, w2hi, w2lo);
  tobf16_chunk<<<(NN * 32 + 255) / 256, 256, 0, stream>>>(feat, hbf, X1);

  // binned CSR build (512-block phases, 391 buckets x 128 nodes)
  zero_i32<<<2, 256, 0, stream>>>(ghist, 512);
  ebin_hist<<<512, 256, 0, stream>>>(dst, ghist);
  ebin_scan<<<1, 512, 0, stream>>>(ghist, gbase, gcur);
  ebin_scatter<<<512, 256, 0, stream>>>(src, dst, gcur, ebin);
  bucket_csr<<<NBUCK, 256, 0, stream>>>(ebin, gbase, cnt, esrcPad);

  // fused agg: 1563 node-groups x 8 (xcd slots); 12504 blocks
  const int aggBlocks = 1563 * 8;
  const int gemBlocks = ((NN + 31) / 32) * 2;  // 3126: 32 rows x 64-col halves

  // layer 1: all 4 chunk passes concurrent, XCD-pinned windows
  agg_all<<<aggBlocks, 256, 0, stream>>>((const unsigned*)hbf, cnt, esrcPad, X1);
  combine_mfma<true, true><<<gemBlocks, 256, 0, stream>>>(X1, w1hi, w1lo, b1,
                                                          nullptr, X2, hbf);

  // layer 2 + FC folded (hbf now holds bf16 relu(h1))
  agg_all<<<aggBlocks, 256, 0, stream>>>((const unsigned*)hbf, cnt, esrcPad, X2);
  combine_mfma<false, false><<<gemBlocks, 256, 0, stream>>>(X2, w2hi, w2lo, bfF,
                                                            out, nullptr, nullptr);
}

// Round 13
// 199.983 us; speedup vs baseline: 1.4885x; 1.3116x over previous
//
#include <hip/hip_runtime.h>
#include <hip/hip_bf16.h>

#define NN 50000
#define NE 1600000
#define F 128
#define CAP 96
#define NBUCK 391   // ceil(NN/128)

typedef short short8 __attribute__((ext_vector_type(8)));
typedef float f32x4 __attribute__((ext_vector_type(4)));
typedef unsigned short u16x4 __attribute__((ext_vector_type(4)));
typedef unsigned short u16x8 __attribute__((ext_vector_type(8)));

__device__ inline unsigned short bf16rne(float f) {
  unsigned u = __builtin_bit_cast(unsigned, f);
  u += 0x7FFFu + ((u >> 16) & 1u);
  return (unsigned short)(u >> 16);
}
__device__ inline float bf16f(unsigned short s) {
  unsigned u = ((unsigned)s) << 16;
  return __builtin_bit_cast(float, u);
}
__device__ inline float bflo(unsigned v) { return __builtin_bit_cast(float, v << 16); }
__device__ inline float bfhi(unsigned v) { return __builtin_bit_cast(float, v & 0xFFFF0000u); }

__global__ void zero_i32(int* __restrict__ p, int n) {
  int i = blockIdx.x * blockDim.x + threadIdx.x;
  if (i < n) p[i] = 0;
}

// O = A @ Wfc  (all 128x128 row-major f32)
__global__ void mat_compose(const float* __restrict__ A, const float* __restrict__ Wfc,
                            float* __restrict__ O) {
  int idx = blockIdx.x * 256 + threadIdx.x;  // < 16384
  int k = idx >> 7, n = idx & 127;
  float s = 0.f;
  for (int j = 0; j < 128; ++j) s += A[k * 128 + j] * Wfc[j * 128 + n];
  O[idx] = s;
}

// bout[n] = sum_k b2[k]*Wfc[k][n] + bfc[n]
__global__ void bias_compose(const float* __restrict__ b2, const float* __restrict__ Wfc,
                             const float* __restrict__ bfc, float* __restrict__ bout) {
  int n = threadIdx.x;  // 128 threads
  float s = bfc[n];
  for (int k = 0; k < 128; ++k) s += b2[k] * Wfc[k * 128 + n];
  bout[n] = s;
}

// ---- 4-phase binned CSR build (bucket = dst>>7, 391 buckets x 128 nodes) ----

__global__ __launch_bounds__(256) void ebin_hist(const int* __restrict__ dst,
                                                 int* __restrict__ ghist) {
  __shared__ int lh[512];
  int t = threadIdx.x;
  lh[t] = 0;
  lh[t + 256] = 0;
  __syncthreads();
  int base = blockIdx.x * 3125;
  for (int k = t; k < 3125; k += 256) atomicAdd(&lh[dst[base + k] >> 7], 1);
  __syncthreads();
  if (t < NBUCK && lh[t]) atomicAdd(&ghist[t], lh[t]);
  int t2 = t + 256;
  if (t2 < NBUCK && lh[t2]) atomicAdd(&ghist[t2], lh[t2]);
}

__global__ void ebin_scan(const int* __restrict__ ghist, int* __restrict__ gbase,
                          int* __restrict__ gcur) {
  __shared__ int s[512];
  int t = threadIdx.x;
  s[t] = (t < NBUCK) ? ghist[t] : 0;
  __syncthreads();
  for (int d = 1; d < 512; d <<= 1) {
    int x = (t >= d) ? s[t - d] : 0;
    __syncthreads();
    s[t] += x;
    __syncthreads();
  }
  int ex = (t == 0) ? 0 : s[t - 1];
  if (t < NBUCK) {
    gbase[t] = ex;
    gcur[t] = ex;
  }
  if (t == NBUCK) gbase[NBUCK] = s[NBUCK - 1];
}

__global__ __launch_bounds__(256) void ebin_scatter(const int* __restrict__ src,
                                                    const int* __restrict__ dst,
                                                    int* __restrict__ gcur,
                                                    unsigned* __restrict__ ebin) {
  __shared__ int lh[512], lbase[512], lcur[512];
  int t = threadIdx.x;
  lh[t] = 0; lh[t + 256] = 0;
  lcur[t] = 0; lcur[t + 256] = 0;
  __syncthreads();
  int base = blockIdx.x * 3125;
  for (int k = t; k < 3125; k += 256) atomicAdd(&lh[dst[base + k] >> 7], 1);
  __syncthreads();
  if (t < NBUCK && lh[t]) lbase[t] = atomicAdd(&gcur[t], lh[t]);
  int t2 = t + 256;
  if (t2 < NBUCK && lh[t2]) lbase[t2] = atomicAdd(&gcur[t2], lh[t2]);
  __syncthreads();
  for (int k = t; k < 3125; k += 256) {
    int d = dst[base + k];
    int b = d >> 7;
    int off = atomicAdd(&lcur[b], 1);
    ebin[lbase[b] + off] = ((unsigned)(d & 127) << 16) | (unsigned)src[base + k];
  }
}

// Phase D: one block per 128-node bucket; rows zero-filled (padding = node 0,
// always valid) so agg gathers full batches unconditionally.
__global__ __launch_bounds__(256) void bucket_csr(const unsigned* __restrict__ ebin,
                                                  const int* __restrict__ gbase,
                                                  int* __restrict__ cnt,
                                                  unsigned short* __restrict__ esrcPad) {
  __shared__ int lcnt[128];
  __shared__ unsigned short rows[128 * CAP];  // 24576 B
  int t = threadIdx.x;
  int b = blockIdx.x;
  if (t < 128) lcnt[t] = 0;
  unsigned* rz = (unsigned*)rows;
  for (int i = t; i < (128 * CAP) / 2; i += 256) rz[i] = 0;
  __syncthreads();
  int s0 = gbase[b], s1 = gbase[b + 1];
  for (int i = s0 + t; i < s1; i += 256) {
    unsigned v = ebin[i];
    int dl = v >> 16;
    int p = atomicAdd(&lcnt[dl], 1);
    if (p < CAP) rows[dl * CAP + p] = (unsigned short)(v & 0xFFFFu);
  }
  __syncthreads();
  int node = b * 128 + t;
  if (t < 128 && node < NN) cnt[node] = lcnt[t];
  int nvalid = min(128, NN - b * 128);
  int limit = (nvalid * CAP) >> 1;  // u32 count
  const unsigned* lsrc = (const unsigned*)rows;
  unsigned* gdst = (unsigned*)(esrcPad + (size_t)b * 128 * CAP);
  for (int i = t; i < limit; i += 256) gdst[i] = lsrc[i];
}

// f32 [node][128] -> bf16 chunked [f/32][node][32] (gather table) AND
// row-major bf16 X[node][256] cols 0..127 (combine A operand)
__global__ void tobf16_chunk(const float* __restrict__ in,
                             unsigned short* __restrict__ chk,
                             unsigned short* __restrict__ X) {
  int i = blockIdx.x * 256 + threadIdx.x;  // i < NN*32
  if (i >= NN * 32) return;
  int node = i >> 5;
  int q = i & 31;            // float4 index within row; f0 = q*4
  int p = q >> 3;            // chunk
  float4 v = ((const float4*)in)[i];
  u16x4 o;
  o[0] = bf16rne(v.x);
  o[1] = bf16rne(v.y);
  o[2] = bf16rne(v.z);
  o[3] = bf16rne(v.w);
  ((u16x4*)chk)[((size_t)p * NN + node) * 8 + (q & 7)] = o;
  *(u16x4*)(X + (size_t)node * 256 + q * 4) = o;
}

// ALL 4 feature-chunk passes in one launch. pass = (blockIdx&7)&3: with
// round-robin block->XCD dispatch each XCD gathers from ONE 3.2MB window.
__global__ __launch_bounds__(256) void agg_all(const unsigned* __restrict__ tbl,
                                               const int* __restrict__ cnt,
                                               const unsigned short* __restrict__ esrcPad,
                                               unsigned short* __restrict__ X) {
  int bid = blockIdx.x;
  int xcd = bid & 7;
  int pass = xcd & 3;
  int nodeBase = (bid >> 3) * 32 + ((xcd >> 2) & 1) * 16;
  int t = threadIdx.x;
  int node = nodeBase + (t >> 4);
  if (node >= NN) return;
  const unsigned* tblp = tbl + (size_t)pass * NN * 16;
  int l = t & 15;
  int e = cnt[node];
  if (e > CAP) e = CAP;
  const unsigned short* ep = esrcPad + (size_t)node * CAP;
  float ax0 = 0.f, ay0 = 0.f, ax1 = 0.f, ay1 = 0.f;
  int nb = (e + 15) >> 4;  // full 16-edge batches, zero-padded
  for (int b = 0; b < nb; ++b) {
    int i = b * 16;
    u16x8 ua = *(const u16x8*)(ep + i);
    u16x8 ub = *(const u16x8*)(ep + i + 8);
    unsigned v[16];
#pragma unroll
    for (int j = 0; j < 8; ++j) v[j] = tblp[(size_t)ua[j] * 16 + l];
#pragma unroll
    for (int j = 0; j < 8; ++j) v[8 + j] = tblp[(size_t)ub[j] * 16 + l];
    int rem = e - i;  // >= 1
#pragma unroll
    for (int j = 0; j < 16; ++j) {
      unsigned x = (j < rem) ? v[j] : 0u;
      if (j & 1) { ax1 += bflo(x); ay1 += bfhi(x); }
      else       { ax0 += bflo(x); ay0 += bfhi(x); }
    }
  }
  float inv = 1.0f / (float)max(e, 1);
  unsigned w = (unsigned)bf16rne((ax0 + ax1) * inv) |
               ((unsigned)bf16rne((ay0 + ay1) * inv) << 16);
  *(unsigned*)(X + (size_t)node * 256 + 128 + pass * 32 + l * 2) = w;
}

// Build transposed bf16 hi/lo weight arrays: WT[n][k], k in [0,256).
__global__ void wprep(const float* __restrict__ Ws, const float* __restrict__ Wn,
                      unsigned short* __restrict__ hi, unsigned short* __restrict__ lo) {
  int i = blockIdx.x * 256 + threadIdx.x;  // < 128*256
  int k = i & 255;
  int n = i >> 8;
  float w = (k < 128) ? Ws[(size_t)k * F + n] : Wn[(size_t)(k - 128) * F + n];
  unsigned short h = bf16rne(w);
  hi[i] = h;
  lo[i] = bf16rne(w - bf16f(h));
}

// C = act(X @ W + bias), X bf16 [NN][256], W hi/lo bf16 [128][256].
// W-IN-LDS: block (512 thr, 8 waves) owns a 64-col half; stages hi+lo slice
// (64KB) into LDS once with XOR-swizzle (col-stride 512B would be a 16-way
// bank conflict otherwise; byte ^= (col&7)<<4 per G4), then each wave does
// one 16-row x 64-col tile: 8 global A-loads + 64 ds_read_b128 + 64 MFMA.
// ds_read's ~12cy throughput replaces the L2 dependent-load chain that
// floored six register-resident variants at 42-53us (compiler re-sank W).
template <bool RELU, bool L1>
__global__ __launch_bounds__(512) void combine_mfma(
    const unsigned short* __restrict__ X,
    const unsigned short* __restrict__ WThi, const unsigned short* __restrict__ WTlo,
    const float* __restrict__ bias, float* __restrict__ Cf,
    unsigned short* __restrict__ Xout, unsigned short* __restrict__ Cb) {
  __shared__ unsigned short whs[64 * 256];  // 32KB
  __shared__ unsigned short wls[64 * 256];  // 32KB
  const int K = 256;
  int t = threadIdx.x;
  int colHalf = blockIdx.x & 1;

  // --- stage W slice (hi+lo) with write-side swizzle ---
  {
    const unsigned short* gh = WThi + (size_t)colHalf * 64 * K;
    const unsigned short* gl = WTlo + (size_t)colHalf * 64 * K;
#pragma unroll
    for (int c = 0; c < 4; ++c) {
      int idx8 = c * 512 + t;          // 16B-chunk id, < 2048
      int cl = idx8 >> 5;              // local col 0..63
      int byte_off = (idx8 & 31) * 16; // byte within col (512B)
      int swz = byte_off ^ ((cl & 7) << 4);
      *(short8*)((char*)whs + cl * 512 + swz) = *(const short8*)(gh + (size_t)idx8 * 8);
      *(short8*)((char*)wls + cl * 512 + swz) = *(const short8*)(gl + (size_t)idx8 * 8);
    }
  }
  __syncthreads();

  int wave = t >> 6;
  int lane = t & 63;
  int lm = lane & 15;  // A row-in-tile / W col-in-tile / C col-in-tile
  int lk = lane >> 4;  // k-chunk select / C row-group
  int R0 = (blockIdx.x >> 1) * 128 + wave * 16;
  if (R0 < NN) {
    int rA = R0 + lm;
    if (rA >= NN) rA = NN - 1;  // clamped rows compute garbage, never stored
    short8 a[8];
    const unsigned short* xp = X + (size_t)rA * K + lk * 8;
#pragma unroll
    for (int ks = 0; ks < 8; ++ks) a[ks] = *(const short8*)(xp + ks * 32);

    f32x4 acc[4];
#pragma unroll
    for (int ct = 0; ct < 4; ++ct) {
      float b = bias[colHalf * 64 + ct * 16 + lm];
      acc[ct] = (f32x4){b, b, b, b};
    }

#pragma unroll
    for (int ct = 0; ct < 4; ++ct) {
      int cl = ct * 16 + lm;
      int cbase = cl * 512;
      int cswz = (cl & 7) << 4;
#pragma unroll
      for (int ks = 0; ks < 8; ++ks) {
        int off = cbase + ((ks * 64 + lk * 16) ^ cswz);
        short8 wh = *(const short8*)((const char*)whs + off);
        short8 wl = *(const short8*)((const char*)wls + off);
        acc[ct] = __builtin_amdgcn_mfma_f32_16x16x32_bf16(a[ks], wh, acc[ct], 0, 0, 0);
        acc[ct] = __builtin_amdgcn_mfma_f32_16x16x32_bf16(a[ks], wl, acc[ct], 0, 0, 0);
      }
    }

#pragma unroll
    for (int ct = 0; ct < 4; ++ct) {
#pragma unroll
      for (int r = 0; r < 4; ++r) {
        int row = R0 + lk * 4 + r;
        if (row < NN) {
          float v = acc[ct][r];
          if (RELU) v = fmaxf(v, 0.f);
          int col = colHalf * 64 + ct * 16 + lm;
          if (L1) {
            unsigned short b = bf16rne(v);
            Xout[(size_t)row * 256 + col] = b;                        // next-layer A
            Cb[((size_t)(col >> 5) * NN + row) * 32 + (col & 31)] = b; // gather table
          } else {
            Cf[(size_t)row * F + col] = v;
          }
        }
      }
    }
  }
}

extern "C" void kernel_launch(void* const* d_in, const int* in_sizes, int n_in,
                              void* d_out, int out_size, void* d_ws, size_t ws_size,
                              hipStream_t stream) {
  const float* feat = (const float*)d_in[0];
  const int* src = (const int*)d_in[1];
  const int* dst = (const int*)d_in[2];
  const float* Ws1 = (const float*)d_in[3];
  const float* Wn1 = (const float*)d_in[4];
  const float* b1 = (const float*)d_in[5];
  const float* Ws2 = (const float*)d_in[6];
  const float* Wn2 = (const float*)d_in[7];
  const float* b2 = (const float*)d_in[8];
  const float* Wfc = (const float*)d_in[9];
  const float* bfc = (const float*)d_in[10];
  float* out = (float*)d_out;

  // workspace layout; every region 16B-aligned
  unsigned short* esrcPad = (unsigned short*)d_ws;        // NN*CAP u16 (9.6MB)
  int* cnt = (int*)(esrcPad + (size_t)NN * CAP);          // 50048 ints
  int* ghist = cnt + 50048;                               // 512
  int* gbase = ghist + 512;                               // 512
  int* gcur = gbase + 512;                                // 512
  unsigned* ebin = (unsigned*)(gcur + 512);               // NE u32 (6.4MB)
  unsigned short* X1 = (unsigned short*)(ebin + NE);      // NN*256 bf16 (25.6MB)
  unsigned short* X2 = X1 + (size_t)NN * 256;             // NN*256 bf16 (25.6MB)
  unsigned short* w1hi = X2 + (size_t)NN * 256;           // 128*256
  unsigned short* w1lo = w1hi + 128 * 256;
  unsigned short* w2hi = w1lo + 128 * 256;
  unsigned short* w2lo = w2hi + 128 * 256;
  float* wsf = (float*)(w2lo + 128 * 256);                // 128*128 f32 (Ws2@Wfc)
  float* wnf = wsf + 128 * 128;                           // 128*128 f32 (Wn2@Wfc)
  float* bfF = wnf + 128 * 128;                           // 128 f32
  unsigned short* hbf = (unsigned short*)(bfF + 128);     // NN*128 bf16 chunked [4][NN][32]

  // fold layer-2 weights through the FC (no nonlinearity between them)
  mat_compose<<<64, 256, 0, stream>>>(Ws2, Wfc, wsf);
  mat_compose<<<64, 256, 0, stream>>>(Wn2, Wfc, wnf);
  bias_compose<<<1, 128, 0, stream>>>(b2, Wfc, bfc, bfF);

  // weight + feature prep (independent of CSR build)
  wprep<<<128, 256, 0, stream>>>(Ws1, Wn1, w1hi, w1lo);
  wprep<<<128, 256, 0, stream>>>(wsf, wnf, w2hi, w2lo);
  tobf16_chunk<<<(NN * 32 + 255) / 256, 256, 0, stream>>>(feat, hbf, X1);

  // binned CSR build (512-block phases, 391 buckets x 128 nodes)
  zero_i32<<<2, 256, 0, stream>>>(ghist, 512);
  ebin_hist<<<512, 256, 0, stream>>>(dst, ghist);
  ebin_scan<<<1, 512, 0, stream>>>(ghist, gbase, gcur);
  ebin_scatter<<<512, 256, 0, stream>>>(src, dst, gcur, ebin);
  bucket_csr<<<NBUCK, 256, 0, stream>>>(ebin, gbase, cnt, esrcPad);

  // fused agg: 1563 node-groups x 8 (xcd slots); 12504 blocks
  const int aggBlocks = 1563 * 8;
  // combine: 512-thr blocks, 128 rows x 64-col half each
  const int gemBlocks = ((NN + 127) / 128) * 2;  // 782

  // layer 1: all 4 chunk passes concurrent, XCD-pinned windows
  agg_all<<<aggBlocks, 256, 0, stream>>>((const unsigned*)hbf, cnt, esrcPad, X1);
  combine_mfma<true, true><<<gemBlocks, 512, 0, stream>>>(X1, w1hi, w1lo, b1,
                                                          nullptr, X2, hbf);

  // layer 2 + FC folded (hbf now holds bf16 relu(h1))
  agg_all<<<aggBlocks, 256, 0, stream>>>((const unsigned*)hbf, cnt, esrcPad, X2);
  combine_mfma<false, false><<<gemBlocks, 512, 0, stream>>>(X2, w2hi, w2lo, bfF,
                                                            out, nullptr, nullptr);
}